// Round 1
// baseline (766.833 us; speedup 1.0000x reference)
//
#include <hip/hip_runtime.h>
#include <hip/hip_bf16.h>
#include <math.h>

typedef float f32x4 __attribute__((ext_vector_type(4)));
typedef short short8 __attribute__((ext_vector_type(8)));

static __device__ __forceinline__ unsigned short f2bf(float f) {
    unsigned u = __builtin_bit_cast(unsigned, f);
    unsigned r = (u + 0x7FFFu + ((u >> 16) & 1u)) >> 16;
    return (unsigned short)r;
}

// ---------------------------------------------------------------------------
// K1a: transpose Ws [E=1024, U=1024] fp32 -> WsT [U, E] bf16
// ---------------------------------------------------------------------------
__global__ __launch_bounds__(256) void wst_kernel(const float* __restrict__ ws,
                                                  unsigned short* __restrict__ wst) {
    __shared__ unsigned short tile[64][65];
    const int e0 = blockIdx.x * 64, u0 = blockIdx.y * 64;
    const int tid = threadIdx.x;
#pragma unroll
    for (int i = 0; i < 16; i++) {
        int idx = i * 256 + tid;
        int r = idx >> 6, c = idx & 63;                  // r: e-local, c: u-local
        tile[r][c] = f2bf(ws[(size_t)(e0 + r) * 1024 + u0 + c]);
    }
    __syncthreads();
#pragma unroll
    for (int i = 0; i < 16; i++) {
        int idx = i * 256 + tid;
        int r = idx >> 6, c = idx & 63;                  // r: u-local, c: e-local
        wst[(size_t)(u0 + r) * 1024 + e0 + c] = tile[c][r];
    }
}

// ---------------------------------------------------------------------------
// K1b: base[b,u] = dec_hidden[b]@Wh_k + Ws_b + Wh_b (+ Wc_b if use_coverage)
// grid (32, 4) x 256
// ---------------------------------------------------------------------------
__global__ __launch_bounds__(256) void base_kernel(const float* __restrict__ dh,
                                                   const float* __restrict__ whk,
                                                   const float* __restrict__ wsb,
                                                   const float* __restrict__ whb,
                                                   const float* __restrict__ wcb,
                                                   const int* __restrict__ ucov,
                                                   float* __restrict__ base) {
    __shared__ float dS[1024];
    const int b = blockIdx.x;
    const int u = blockIdx.y * 256 + threadIdx.x;
    for (int i = threadIdx.x; i < 1024; i += 256) dS[i] = dh[b * 1024 + i];
    __syncthreads();
    float acc = wsb[u] + whb[u] + ((*ucov) ? wcb[u] : 0.f);
#pragma unroll 8
    for (int e = 0; e < 1024; e++) acc = fmaf(dS[e], whk[(size_t)e * 1024 + u], acc);
    base[b * 1024 + u] = acc;
}

// ---------------------------------------------------------------------------
// K2: fused GEMM + tanh + dot(V): score partials
// pre[row,u] = enc[row,:]@Ws[:,u] + base[b,u] + cov[row]*Wc[u]
// score[row] += sum_u tanh(pre)*V[u]    (atomicAdd over 8 u-tiles)
// grid (8 u-tiles, 512 m-tiles) x 256 threads (4 waves, 2x2 of 64x64)
// ---------------------------------------------------------------------------
#define BM 128
#define BN 128
#define BK 32
#define LDT 40   // padded LDS stride (bf16 elems): 80B -> 20-bank shift, 2-way free

__global__ __launch_bounds__(256) void score_gemm_kernel(
    const float* __restrict__ enc,            // [65536,1024] fp32
    const unsigned short* __restrict__ wst,   // [1024,1024] bf16 (u-major)
    const float* __restrict__ base,           // [32,1024]
    const float* __restrict__ cov,            // [32,2048]
    const float* __restrict__ wc,             // [1024]
    const float* __restrict__ vk,             // [1024]
    const int* __restrict__ ucov,
    float* __restrict__ score)                // [65536]
{
    __shared__ unsigned short As[BM * LDT];
    __shared__ unsigned short Bs[BN * LDT];
    __shared__ float covS[BM];

    const int tid  = threadIdx.x;
    const int u0   = blockIdx.x * BN;
    const int row0 = blockIdx.y * BM;
    const int b    = row0 >> 11;              // /2048; BM|L so one b per block
    const int use_cov = *ucov;

    if (tid < BM) covS[tid] = use_cov ? cov[row0 + tid] : 0.f;

    const int lane = tid & 63;
    const int wid  = tid >> 6;
    const int wm   = wid >> 1, wn = wid & 1;
    const int l16  = lane & 15, quad = lane >> 4;

    f32x4 acc[4][4] = {};

    for (int k0 = 0; k0 < 1024; k0 += BK) {
        __syncthreads();
        // stage A: 128x32 fp32 -> bf16 (4 float4 per thread)
#pragma unroll
        for (int i = 0; i < 4; i++) {
            int f = i * 256 + tid;
            int r = f >> 3, c4 = f & 7;
            const float* p = enc + (size_t)(row0 + r) * 1024 + k0 + c4 * 4;
            float x0 = p[0], x1 = p[1], x2 = p[2], x3 = p[3];
            ushort4 w;
            w.x = f2bf(x0); w.y = f2bf(x1); w.z = f2bf(x2); w.w = f2bf(x3);
            *(ushort4*)&As[r * LDT + c4 * 4] = w;
        }
        // stage B: 128x32 bf16 (2 x 16B per thread)
#pragma unroll
        for (int i = 0; i < 2; i++) {
            int f = i * 256 + tid;
            int r = f >> 2, c8 = f & 3;
            uint4 w = *(const uint4*)(wst + (size_t)(u0 + r) * 1024 + k0 + c8 * 8);
            *(uint4*)&Bs[r * LDT + c8 * 8] = w;
        }
        __syncthreads();

        short8 a[4], bb[4];
#pragma unroll
        for (int t = 0; t < 4; t++) {
            int ra = wm * 64 + t * 16 + l16;
            a[t]  = *(const short8*)&As[ra * LDT + quad * 8];
            int rb = wn * 64 + t * 16 + l16;
            bb[t] = *(const short8*)&Bs[rb * LDT + quad * 8];
        }
#pragma unroll
        for (int i = 0; i < 4; i++)
#pragma unroll
            for (int j = 0; j < 4; j++)
                acc[i][j] = __builtin_amdgcn_mfma_f32_16x16x32_bf16(a[i], bb[j], acc[i][j], 0, 0, 0);
    }

    // epilogue: tanh(acc + base + cov*Wc) * V, reduce over the 128 u's here
    float basev[4], wcv[4], vv[4];
#pragma unroll
    for (int j = 0; j < 4; j++) {
        int u = u0 + wn * 64 + j * 16 + l16;
        basev[j] = base[b * 1024 + u];
        wcv[j]   = use_cov ? wc[u] : 0.f;
        vv[j]    = vk[u];
    }
#pragma unroll
    for (int i = 0; i < 4; i++) {
        float part[4] = {0.f, 0.f, 0.f, 0.f};
#pragma unroll
        for (int r = 0; r < 4; r++) {
            int rl = wm * 64 + i * 16 + quad * 4 + r;
            float cv = covS[rl];
#pragma unroll
            for (int j = 0; j < 4; j++) {
                float pre = acc[i][j][r] + basev[j] + cv * wcv[j];
                part[r] += tanhf(pre) * vv[j];
            }
        }
#pragma unroll
        for (int r = 0; r < 4; r++) {
            float v = part[r];
            v += __shfl_xor(v, 1);
            v += __shfl_xor(v, 2);
            v += __shfl_xor(v, 4);
            v += __shfl_xor(v, 8);
            if (l16 == 0)
                atomicAdd(&score[row0 + wm * 64 + i * 16 + quad * 4 + r], v);
        }
    }
}

// ---------------------------------------------------------------------------
// K3: softmax over L per b; writes attn and coverage outputs
// grid 32 x 1024 threads (2 elems/thread)
// ---------------------------------------------------------------------------
__global__ __launch_bounds__(1024) void softmax_kernel(
    const float* __restrict__ score, const float* __restrict__ vb,
    const int* __restrict__ mask, const float* __restrict__ cov,
    const int* __restrict__ ucov,
    float* __restrict__ attn_out, float* __restrict__ cov_out)
{
    __shared__ float redA[16], redB[16];
    __shared__ float bc0, bc1;
    const int b = blockIdx.x, tid = threadIdx.x;
    const int i0 = b * 2048 + tid, i1 = i0 + 1024;
    const float vbv = vb[0];
    const int uc = *ucov;

    float s0 = (score[i0] + vbv) * (float)mask[i0];
    float s1 = (score[i1] + vbv) * (float)mask[i1];

    // max reduce
    float m = fmaxf(s0, s1);
#pragma unroll
    for (int off = 1; off < 64; off <<= 1) m = fmaxf(m, __shfl_xor(m, off));
    if ((tid & 63) == 0) redA[tid >> 6] = m;
    __syncthreads();
    if (tid < 16) {
        float v = redA[tid];
#pragma unroll
        for (int off = 1; off < 16; off <<= 1) v = fmaxf(v, __shfl_xor(v, off));
        if (tid == 0) bc0 = v;
    }
    __syncthreads();
    const float M = bc0;

    float e0 = expf(s0 - M), e1 = expf(s1 - M);
    float s = e0 + e1;
#pragma unroll
    for (int off = 1; off < 64; off <<= 1) s += __shfl_xor(s, off);
    if ((tid & 63) == 0) redB[tid >> 6] = s;
    __syncthreads();
    if (tid < 16) {
        float v = redB[tid];
#pragma unroll
        for (int off = 1; off < 16; off <<= 1) v += __shfl_xor(v, off);
        if (tid == 0) bc1 = v;
    }
    __syncthreads();
    const float inv = 1.f / bc1;

    float a0 = e0 * inv, a1 = e1 * inv;
    attn_out[i0] = a0;
    attn_out[i1] = a1;
    cov_out[i0] = a0 + (uc ? cov[i0] : 0.f);
    cov_out[i1] = a1 + (uc ? cov[i1] : 0.f);
}

// ---------------------------------------------------------------------------
// K4: context[b,e] = sum_l attn[b,l]*enc[b,l,e]; grid (32, 16) x 256
// ---------------------------------------------------------------------------
__global__ __launch_bounds__(256) void context_kernel(const float* __restrict__ enc,
                                                      const float* __restrict__ attn,
                                                      float* __restrict__ ctx) {
    __shared__ float aS[128];
    const int b = blockIdx.x, lc = blockIdx.y, tid = threadIdx.x;
    const int l0 = lc * 128;
    if (tid < 128) aS[tid] = attn[b * 2048 + l0 + tid];
    __syncthreads();
    const float* p = enc + ((size_t)(b * 2048 + l0)) * 1024 + tid * 4;
    f32x4 acc = {0.f, 0.f, 0.f, 0.f};
#pragma unroll 4
    for (int l = 0; l < 128; l++) {
        f32x4 e = *(const f32x4*)(p + (size_t)l * 1024);
        acc += e * aS[l];
    }
    float* o = ctx + b * 1024 + tid * 4;
    atomicAdd(o + 0, acc.x);
    atomicAdd(o + 1, acc.y);
    atomicAdd(o + 2, acc.z);
    atomicAdd(o + 3, acc.w);
}

// ---------------------------------------------------------------------------
extern "C" void kernel_launch(void* const* d_in, const int* in_sizes, int n_in,
                              void* d_out, int out_size, void* d_ws, size_t ws_size,
                              hipStream_t stream) {
    const float* dec_hidden = (const float*)d_in[0];   // [32,1024]
    const float* enc        = (const float*)d_in[1];   // [32,2048,1024]
    const float* prev_cov   = (const float*)d_in[2];   // [32,2048,1]
    const float* Ws_k       = (const float*)d_in[3];   // [1024,1024]
    const float* Ws_b       = (const float*)d_in[4];   // [1024]
    const float* Wh_k       = (const float*)d_in[5];   // [1024,1024]
    const float* Wh_b       = (const float*)d_in[6];   // [1024]
    const float* Wc_k       = (const float*)d_in[7];   // [1,1024]
    const float* Wc_b       = (const float*)d_in[8];   // [1024]
    const float* V_k        = (const float*)d_in[9];   // [1024,1]
    const float* V_b        = (const float*)d_in[10];  // [1]
    const int*   mask       = (const int*)d_in[11];    // [32,2048]
    const int*   ucov       = (const int*)d_in[12];    // scalar

    float* out_ctx  = (float*)d_out;            // 32*1024
    float* out_attn = out_ctx + 32 * 1024;      // 65536
    float* out_cov  = out_attn + 65536;         // 65536

    char* ws = (char*)d_ws;
    unsigned short* wst = (unsigned short*)ws;                       // 2 MB
    float* base  = (float*)(ws + (2u << 20));                        // 128 KB
    float* score = (float*)(ws + (2u << 20) + (128u << 10));         // 256 KB

    hipMemsetAsync(score, 0, 65536 * sizeof(float), stream);
    hipMemsetAsync(out_ctx, 0, 32 * 1024 * sizeof(float), stream);

    wst_kernel<<<dim3(16, 16), 256, 0, stream>>>(Ws_k, wst);
    base_kernel<<<dim3(32, 4), 256, 0, stream>>>(dec_hidden, Wh_k, Ws_b, Wh_b, Wc_b, ucov, base);
    score_gemm_kernel<<<dim3(8, 512), 256, 0, stream>>>(enc, wst, base, prev_cov, Wc_k, V_k, ucov, score);
    softmax_kernel<<<32, 1024, 0, stream>>>(score, V_b, mask, prev_cov, ucov, out_attn, out_cov);
    context_kernel<<<dim3(32, 16), 256, 0, stream>>>(enc, out_attn, out_ctx);
}

// Round 2
// 693.821 us; speedup vs baseline: 1.1052x; 1.1052x over previous
//
#include <hip/hip_runtime.h>
#include <hip/hip_bf16.h>
#include <math.h>

typedef float f32x4 __attribute__((ext_vector_type(4)));
typedef short short8 __attribute__((ext_vector_type(8)));
typedef unsigned short u16x8 __attribute__((ext_vector_type(8)));

static __device__ __forceinline__ unsigned short f2bf(float f) {
    unsigned u = __builtin_bit_cast(unsigned, f);
    unsigned r = (u + 0x7FFFu + ((u >> 16) & 1u)) >> 16;
    return (unsigned short)r;
}
static __device__ __forceinline__ float bf2f(unsigned short h) {
    unsigned u = ((unsigned)h) << 16;
    return __builtin_bit_cast(float, u);
}
static __device__ __forceinline__ float fast_tanh(float x) {
    float ax = fminf(fmaxf(x, -9.f), 9.f);
    float e = __expf(2.f * ax);
    return 1.f - 2.f / (e + 1.f);
}

#define GLD16(g, l) __builtin_amdgcn_global_load_lds(                        \
    (const __attribute__((address_space(1))) void*)(g),                      \
    (__attribute__((address_space(3))) void*)(l), 16, 0, 0)

// ---------------------------------------------------------------------------
// K0: enc fp32 -> bf16 (64M elems, 16 per thread). grid 16384 x 256
// ---------------------------------------------------------------------------
__global__ __launch_bounds__(256) void conv_kernel(const float* __restrict__ in,
                                                   unsigned short* __restrict__ out) {
    size_t g = ((size_t)blockIdx.x * 256 + threadIdx.x) * 16;
    const f32x4* p = (const f32x4*)(in + g);
    f32x4 v0 = p[0], v1 = p[1], v2 = p[2], v3 = p[3];
    u16x8 w0, w1;
    w0[0] = f2bf(v0.x); w0[1] = f2bf(v0.y); w0[2] = f2bf(v0.z); w0[3] = f2bf(v0.w);
    w0[4] = f2bf(v1.x); w0[5] = f2bf(v1.y); w0[6] = f2bf(v1.z); w0[7] = f2bf(v1.w);
    w1[0] = f2bf(v2.x); w1[1] = f2bf(v2.y); w1[2] = f2bf(v2.z); w1[3] = f2bf(v2.w);
    w1[4] = f2bf(v3.x); w1[5] = f2bf(v3.y); w1[6] = f2bf(v3.z); w1[7] = f2bf(v3.w);
    *(u16x8*)(out + g) = w0;
    *(u16x8*)(out + g + 8) = w1;
}

// ---------------------------------------------------------------------------
// K1a: transpose Ws [E,U] fp32 -> WsT [U,E] bf16. grid (16,16) x 256
// ---------------------------------------------------------------------------
__global__ __launch_bounds__(256) void wst_kernel(const float* __restrict__ ws,
                                                  unsigned short* __restrict__ wst) {
    __shared__ unsigned short tile[64][65];
    const int e0 = blockIdx.x * 64, u0 = blockIdx.y * 64;
    const int tid = threadIdx.x;
#pragma unroll
    for (int i = 0; i < 16; i++) {
        int idx = i * 256 + tid;
        int r = idx >> 6, c = idx & 63;
        tile[r][c] = f2bf(ws[(size_t)(e0 + r) * 1024 + u0 + c]);
    }
    __syncthreads();
#pragma unroll
    for (int i = 0; i < 16; i++) {
        int idx = i * 256 + tid;
        int r = idx >> 6, c = idx & 63;
        wst[(size_t)(u0 + r) * 1024 + e0 + c] = tile[c][r];
    }
}

// ---------------------------------------------------------------------------
// K1b: base[b,u] += sum_e dec[b,e]*Wh[e,u], e-split for parallelism.
// grid (32 b, 8 e-chunks) x 256; base must be zeroed. Biases added in epilogue.
// ---------------------------------------------------------------------------
__global__ __launch_bounds__(256) void base_kernel(const float* __restrict__ dh,
                                                   const float* __restrict__ whk,
                                                   float* __restrict__ base) {
    __shared__ float dS[128];
    const int b = blockIdx.x, e0 = blockIdx.y * 128, tid = threadIdx.x;
    if (tid < 128) dS[tid] = dh[b * 1024 + e0 + tid];
    __syncthreads();
    f32x4 acc = {0.f, 0.f, 0.f, 0.f};
#pragma unroll 4
    for (int e = 0; e < 128; e++)
        acc += dS[e] * *(const f32x4*)(whk + (size_t)(e0 + e) * 1024 + tid * 4);
    float* o = base + b * 1024 + tid * 4;
    atomicAdd(o + 0, acc.x);
    atomicAdd(o + 1, acc.y);
    atomicAdd(o + 2, acc.z);
    atomicAdd(o + 3, acc.w);
}

// ---------------------------------------------------------------------------
// K2 (fast): fused GEMM + tanh + dot(V) with bf16 enc + global_load_lds.
// LDS layout: row-major [128][32] bf16, 16B chunk c of row r stored at slot
// r*4 + ((c + r + (r>>2)) & 3)  -> ds_read_b128 2-way (free) bank pattern.
// grid (8 u-tiles, 512 m-tiles) x 256
// ---------------------------------------------------------------------------
#define BM 128
#define BN 128
#define BK 32

__global__ __launch_bounds__(256) void score_gemm_fast(
    const unsigned short* __restrict__ encB,  // [65536,1024] bf16
    const unsigned short* __restrict__ wst,   // [1024,1024] bf16 (u-major)
    const float* __restrict__ base,           // [32,1024] (no biases)
    const float* __restrict__ cov,            // [32,2048]
    const float* __restrict__ wc,             // [1024]
    const float* __restrict__ vk,             // [1024]
    const float* __restrict__ wsb, const float* __restrict__ whb,
    const float* __restrict__ wcb,
    const int* __restrict__ ucov,
    float* __restrict__ score)                // [65536]
{
    __shared__ unsigned short As[BM * BK];    // 8 KB
    __shared__ unsigned short Bs[BN * BK];    // 8 KB
    __shared__ float covS[BM];

    const int tid  = threadIdx.x;
    const int u0   = blockIdx.x * BN;
    const int row0 = blockIdx.y * BM;
    const int b    = row0 >> 11;
    const int use_cov = *ucov;

    if (tid < BM) covS[tid] = use_cov ? cov[row0 + tid] : 0.f;

    const int lane = tid & 63;
    const int wid  = tid >> 6;
    const int wm   = wid >> 1, wn = wid & 1;
    const int l16  = lane & 15, quad = lane >> 4;

    // staging: thread owns LDS slots f0 = tid, f1 = 256+tid (16B units)
    const int f0 = tid, f1 = 256 + tid;
    const int rA0 = f0 >> 2, rA1 = f1 >> 2;
    const int cA0 = ((f0 & 3) - rA0 - (rA0 >> 2)) & 3;
    const int cA1 = ((f1 & 3) - rA1 - (rA1 >> 2)) & 3;
    const unsigned short* pA0 = encB + (size_t)(row0 + rA0) * 1024 + cA0 * 8;
    const unsigned short* pA1 = encB + (size_t)(row0 + rA1) * 1024 + cA1 * 8;
    const unsigned short* pB0 = wst + (size_t)(u0 + rA0) * 1024 + cA0 * 8;
    const unsigned short* pB1 = wst + (size_t)(u0 + rA1) * 1024 + cA1 * 8;
    unsigned short* dA0 = As + f0 * 8;
    unsigned short* dA1 = As + f1 * 8;
    unsigned short* dB0 = Bs + f0 * 8;
    unsigned short* dB1 = Bs + f1 * 8;

    // fragment LDS offsets (elems)
    int offA[4], offB[4];
#pragma unroll
    for (int t = 0; t < 4; t++) {
        int ra = wm * 64 + t * 16 + l16;
        offA[t] = (ra * 4 + ((quad + ra + (ra >> 2)) & 3)) * 8;
        int rb = wn * 64 + t * 16 + l16;
        offB[t] = (rb * 4 + ((quad + rb + (rb >> 2)) & 3)) * 8;
    }

    f32x4 acc[4][4] = {};

    for (int kk = 0; kk < 1024 / BK; kk++) {
        __syncthreads();
        GLD16(pA0, dA0);
        GLD16(pA1, dA1);
        GLD16(pB0, dB0);
        GLD16(pB1, dB1);
        pA0 += BK; pA1 += BK; pB0 += BK; pB1 += BK;
        __syncthreads();

        short8 a[4], bb[4];
#pragma unroll
        for (int t = 0; t < 4; t++) {
            a[t]  = *(const short8*)&As[offA[t]];
            bb[t] = *(const short8*)&Bs[offB[t]];
        }
#pragma unroll
        for (int i = 0; i < 4; i++)
#pragma unroll
            for (int j = 0; j < 4; j++)
                acc[i][j] = __builtin_amdgcn_mfma_f32_16x16x32_bf16(a[i], bb[j], acc[i][j], 0, 0, 0);
    }

    float basev[4], wcv[4], vv[4];
#pragma unroll
    for (int j = 0; j < 4; j++) {
        int u = u0 + wn * 64 + j * 16 + l16;
        basev[j] = base[b * 1024 + u] + wsb[u] + whb[u] + (use_cov ? wcb[u] : 0.f);
        wcv[j]   = use_cov ? wc[u] : 0.f;
        vv[j]    = vk[u];
    }
#pragma unroll
    for (int i = 0; i < 4; i++) {
        float part[4] = {0.f, 0.f, 0.f, 0.f};
#pragma unroll
        for (int r = 0; r < 4; r++) {
            int rl = wm * 64 + i * 16 + quad * 4 + r;
            float cv = covS[rl];
#pragma unroll
            for (int j = 0; j < 4; j++) {
                float pre = acc[i][j][r] + basev[j] + cv * wcv[j];
                part[r] += fast_tanh(pre) * vv[j];
            }
        }
#pragma unroll
        for (int r = 0; r < 4; r++) {
            float v = part[r];
            v += __shfl_xor(v, 1);
            v += __shfl_xor(v, 2);
            v += __shfl_xor(v, 4);
            v += __shfl_xor(v, 8);
            if (l16 == 0)
                atomicAdd(&score[row0 + wm * 64 + i * 16 + quad * 4 + r], v);
        }
    }
}

// ---------------------------------------------------------------------------
// K2 (fallback, fp32 staging) — used only if ws_size too small for enc bf16.
// ---------------------------------------------------------------------------
#define LDT 40
__global__ __launch_bounds__(256) void score_gemm_f32(
    const float* __restrict__ enc, const unsigned short* __restrict__ wst,
    const float* __restrict__ base, const float* __restrict__ cov,
    const float* __restrict__ wc, const float* __restrict__ vk,
    const float* __restrict__ wsb, const float* __restrict__ whb,
    const float* __restrict__ wcb,
    const int* __restrict__ ucov, float* __restrict__ score)
{
    __shared__ unsigned short As[BM * LDT];
    __shared__ unsigned short Bs[BN * LDT];
    __shared__ float covS[BM];
    const int tid = threadIdx.x;
    const int u0 = blockIdx.x * BN, row0 = blockIdx.y * BM;
    const int b = row0 >> 11;
    const int use_cov = *ucov;
    if (tid < BM) covS[tid] = use_cov ? cov[row0 + tid] : 0.f;
    const int lane = tid & 63, wid = tid >> 6;
    const int wm = wid >> 1, wn = wid & 1;
    const int l16 = lane & 15, quad = lane >> 4;
    f32x4 acc[4][4] = {};
    for (int k0 = 0; k0 < 1024; k0 += BK) {
        __syncthreads();
#pragma unroll
        for (int i = 0; i < 4; i++) {
            int f = i * 256 + tid;
            int r = f >> 3, c4 = f & 7;
            const float* p = enc + (size_t)(row0 + r) * 1024 + k0 + c4 * 4;
            ushort4 w;
            w.x = f2bf(p[0]); w.y = f2bf(p[1]); w.z = f2bf(p[2]); w.w = f2bf(p[3]);
            *(ushort4*)&As[r * LDT + c4 * 4] = w;
        }
#pragma unroll
        for (int i = 0; i < 2; i++) {
            int f = i * 256 + tid;
            int r = f >> 2, c8 = f & 3;
            uint4 w = *(const uint4*)(wst + (size_t)(u0 + r) * 1024 + k0 + c8 * 8);
            *(uint4*)&Bs[r * LDT + c8 * 8] = w;
        }
        __syncthreads();
        short8 a[4], bb[4];
#pragma unroll
        for (int t = 0; t < 4; t++) {
            a[t]  = *(const short8*)&As[(wm * 64 + t * 16 + l16) * LDT + quad * 8];
            bb[t] = *(const short8*)&Bs[(wn * 64 + t * 16 + l16) * LDT + quad * 8];
        }
#pragma unroll
        for (int i = 0; i < 4; i++)
#pragma unroll
            for (int j = 0; j < 4; j++)
                acc[i][j] = __builtin_amdgcn_mfma_f32_16x16x32_bf16(a[i], bb[j], acc[i][j], 0, 0, 0);
    }
    float basev[4], wcv[4], vv[4];
#pragma unroll
    for (int j = 0; j < 4; j++) {
        int u = u0 + wn * 64 + j * 16 + l16;
        basev[j] = base[b * 1024 + u] + wsb[u] + whb[u] + (use_cov ? wcb[u] : 0.f);
        wcv[j] = use_cov ? wc[u] : 0.f;
        vv[j] = vk[u];
    }
#pragma unroll
    for (int i = 0; i < 4; i++) {
        float part[4] = {0.f, 0.f, 0.f, 0.f};
#pragma unroll
        for (int r = 0; r < 4; r++) {
            float cv = covS[wm * 64 + i * 16 + quad * 4 + r];
#pragma unroll
            for (int j = 0; j < 4; j++)
                part[r] += fast_tanh(acc[i][j][r] + basev[j] + cv * wcv[j]) * vv[j];
        }
#pragma unroll
        for (int r = 0; r < 4; r++) {
            float v = part[r];
            v += __shfl_xor(v, 1);
            v += __shfl_xor(v, 2);
            v += __shfl_xor(v, 4);
            v += __shfl_xor(v, 8);
            if (l16 == 0)
                atomicAdd(&score[row0 + wm * 64 + i * 16 + quad * 4 + r], v);
        }
    }
}

// ---------------------------------------------------------------------------
// K3: softmax over L per b. grid 32 x 1024
// ---------------------------------------------------------------------------
__global__ __launch_bounds__(1024) void softmax_kernel(
    const float* __restrict__ score, const float* __restrict__ vb,
    const int* __restrict__ mask, const float* __restrict__ cov,
    const int* __restrict__ ucov,
    float* __restrict__ attn_out, float* __restrict__ cov_out)
{
    __shared__ float redA[16], redB[16];
    __shared__ float bc0, bc1;
    const int b = blockIdx.x, tid = threadIdx.x;
    const int i0 = b * 2048 + tid, i1 = i0 + 1024;
    const float vbv = vb[0];
    const int uc = *ucov;

    float s0 = (score[i0] + vbv) * (float)mask[i0];
    float s1 = (score[i1] + vbv) * (float)mask[i1];

    float m = fmaxf(s0, s1);
#pragma unroll
    for (int off = 1; off < 64; off <<= 1) m = fmaxf(m, __shfl_xor(m, off));
    if ((tid & 63) == 0) redA[tid >> 6] = m;
    __syncthreads();
    if (tid < 16) {
        float v = redA[tid];
#pragma unroll
        for (int off = 1; off < 16; off <<= 1) v = fmaxf(v, __shfl_xor(v, off));
        if (tid == 0) bc0 = v;
    }
    __syncthreads();
    const float M = bc0;

    float e0 = __expf(s0 - M), e1 = __expf(s1 - M);
    float s = e0 + e1;
#pragma unroll
    for (int off = 1; off < 64; off <<= 1) s += __shfl_xor(s, off);
    if ((tid & 63) == 0) redB[tid >> 6] = s;
    __syncthreads();
    if (tid < 16) {
        float v = redB[tid];
#pragma unroll
        for (int off = 1; off < 16; off <<= 1) v += __shfl_xor(v, off);
        if (tid == 0) bc1 = v;
    }
    __syncthreads();
    const float inv = 1.f / bc1;

    float a0 = e0 * inv, a1 = e1 * inv;
    attn_out[i0] = a0;
    attn_out[i1] = a1;
    cov_out[i0] = a0 + (uc ? cov[i0] : 0.f);
    cov_out[i1] = a1 + (uc ? cov[i1] : 0.f);
}

// ---------------------------------------------------------------------------
// K4 (fast): context from bf16 enc. grid (32 b, 16 l-chunks) x 256.
// thread: e-range 8 wide, covers rows l0+r0, l0+r0+2, ...
// ---------------------------------------------------------------------------
__global__ __launch_bounds__(256) void context_bf16(const unsigned short* __restrict__ encB,
                                                    const float* __restrict__ attn,
                                                    float* __restrict__ ctx) {
    __shared__ float aS[128];
    const int b = blockIdx.x, lc = blockIdx.y, tid = threadIdx.x;
    const int l0 = lc * 128;
    if (tid < 128) aS[tid] = attn[b * 2048 + l0 + tid];
    __syncthreads();
    const int e8 = (tid & 127) * 8, r0 = tid >> 7;
    float acc[8] = {};
#pragma unroll 4
    for (int l = r0; l < 128; l += 2) {
        u16x8 w = *(const u16x8*)(encB + (size_t)(b * 2048 + l0 + l) * 1024 + e8);
        float a = aS[l];
#pragma unroll
        for (int j = 0; j < 8; j++) acc[j] = fmaf(a, bf2f(w[j]), acc[j]);
    }
    float* o = ctx + b * 1024 + e8;
#pragma unroll
    for (int j = 0; j < 8; j++) atomicAdd(o + j, acc[j]);
}

// K4 (fallback): fp32 enc
__global__ __launch_bounds__(256) void context_f32(const float* __restrict__ enc,
                                                   const float* __restrict__ attn,
                                                   float* __restrict__ ctx) {
    __shared__ float aS[128];
    const int b = blockIdx.x, lc = blockIdx.y, tid = threadIdx.x;
    const int l0 = lc * 128;
    if (tid < 128) aS[tid] = attn[b * 2048 + l0 + tid];
    __syncthreads();
    const float* p = enc + ((size_t)(b * 2048 + l0)) * 1024 + tid * 4;
    f32x4 acc = {0.f, 0.f, 0.f, 0.f};
#pragma unroll 4
    for (int l = 0; l < 128; l++) acc += *(const f32x4*)(p + (size_t)l * 1024) * aS[l];
    float* o = ctx + b * 1024 + tid * 4;
    atomicAdd(o + 0, acc.x);
    atomicAdd(o + 1, acc.y);
    atomicAdd(o + 2, acc.z);
    atomicAdd(o + 3, acc.w);
}

// ---------------------------------------------------------------------------
extern "C" void kernel_launch(void* const* d_in, const int* in_sizes, int n_in,
                              void* d_out, int out_size, void* d_ws, size_t ws_size,
                              hipStream_t stream) {
    const float* dec_hidden = (const float*)d_in[0];
    const float* enc        = (const float*)d_in[1];
    const float* prev_cov   = (const float*)d_in[2];
    const float* Ws_k       = (const float*)d_in[3];
    const float* Ws_b       = (const float*)d_in[4];
    const float* Wh_k       = (const float*)d_in[5];
    const float* Wh_b       = (const float*)d_in[6];
    const float* Wc_k       = (const float*)d_in[7];
    const float* Wc_b       = (const float*)d_in[8];
    const float* V_k        = (const float*)d_in[9];
    const float* V_b        = (const float*)d_in[10];
    const int*   mask       = (const int*)d_in[11];
    const int*   ucov       = (const int*)d_in[12];

    float* out_ctx  = (float*)d_out;
    float* out_attn = out_ctx + 32 * 1024;
    float* out_cov  = out_attn + 65536;

    char* ws = (char*)d_ws;
    unsigned short* wst = (unsigned short*)ws;                 // 2 MB
    float* base  = (float*)(ws + 2097152);                     // 128 KB
    float* score = (float*)(ws + 2097152 + 131072);            // 256 KB
    unsigned short* encB = (unsigned short*)(ws + 2490368);    // 128 MB
    const size_t need_fast = 2490368 + (size_t)32 * 2048 * 1024 * 2;

    hipMemsetAsync(score, 0, 65536 * sizeof(float), stream);
    hipMemsetAsync(base, 0, 32 * 1024 * sizeof(float), stream);
    hipMemsetAsync(out_ctx, 0, 32 * 1024 * sizeof(float), stream);

    wst_kernel<<<dim3(16, 16), 256, 0, stream>>>(Ws_k, wst);
    base_kernel<<<dim3(32, 8), 256, 0, stream>>>(dec_hidden, Wh_k, base);

    if (ws_size >= need_fast) {
        conv_kernel<<<16384, 256, 0, stream>>>(enc, encB);
        score_gemm_fast<<<dim3(8, 512), 256, 0, stream>>>(
            encB, wst, base, prev_cov, Wc_k, V_k, Ws_b, Wh_b, Wc_b, ucov, score);
        softmax_kernel<<<32, 1024, 0, stream>>>(score, V_b, mask, prev_cov, ucov, out_attn, out_cov);
        context_bf16<<<dim3(32, 16), 256, 0, stream>>>(encB, out_attn, out_ctx);
    } else {
        score_gemm_f32<<<dim3(8, 512), 256, 0, stream>>>(
            enc, wst, base, prev_cov, Wc_k, V_k, Ws_b, Wh_b, Wc_b, ucov, score);
        softmax_kernel<<<32, 1024, 0, stream>>>(score, V_b, mask, prev_cov, ucov, out_attn, out_cov);
        context_f32<<<dim3(32, 16), 256, 0, stream>>>(enc, out_attn, out_ctx);
    }
}

// Round 3
// 668.830 us; speedup vs baseline: 1.1465x; 1.0374x over previous
//
#include <hip/hip_runtime.h>
#include <hip/hip_bf16.h>
#include <math.h>

typedef float f32x4 __attribute__((ext_vector_type(4)));
typedef short short8 __attribute__((ext_vector_type(8)));
typedef unsigned short u16x8 __attribute__((ext_vector_type(8)));

static __device__ __forceinline__ unsigned short f2bf(float f) {
    unsigned u = __builtin_bit_cast(unsigned, f);
    unsigned r = (u + 0x7FFFu + ((u >> 16) & 1u)) >> 16;
    return (unsigned short)r;
}
static __device__ __forceinline__ float bf2f(unsigned short h) {
    unsigned u = ((unsigned)h) << 16;
    return __builtin_bit_cast(float, u);
}
static __device__ __forceinline__ float fast_tanh(float x) {
    float ax = fminf(fmaxf(x, -9.f), 9.f);
    float e = __expf(2.f * ax);
    return 1.f - 2.f / (e + 1.f);
}

#define GLD16(g, l) __builtin_amdgcn_global_load_lds(                        \
    (const __attribute__((address_space(1))) void*)(g),                      \
    (__attribute__((address_space(3))) void*)(l), 16, 0, 0)

// ---------------------------------------------------------------------------
// PREP (fused): blocks [0,16384): enc fp32->bf16 (coalesced 16B/lane);
// [16384,16640): Ws transpose->bf16; [16640,16896): base partials (8 e-chunks)
// ---------------------------------------------------------------------------
__global__ __launch_bounds__(256) void prep_kernel(
    const float* __restrict__ enc, unsigned short* __restrict__ encB,
    const float* __restrict__ ws, unsigned short* __restrict__ wst,
    const float* __restrict__ dh, const float* __restrict__ whk,
    float* __restrict__ base_part)
{
    __shared__ unsigned short tile[64][65];
    __shared__ float dS[128];
    const int bid = blockIdx.x, tid = threadIdx.x;

    if (bid < 16384) {
        const size_t base0 = (size_t)bid * 4096;
#pragma unroll
        for (int i = 0; i < 4; i++) {
            size_t g = base0 + (size_t)i * 1024 + tid * 4;
            f32x4 v = *(const f32x4*)(enc + g);
            ushort4 w;
            w.x = f2bf(v.x); w.y = f2bf(v.y); w.z = f2bf(v.z); w.w = f2bf(v.w);
            *(ushort4*)(encB + g) = w;
        }
    } else if (bid < 16640) {
        const int b2 = bid - 16384;
        const int e0 = (b2 & 15) * 64, u0 = (b2 >> 4) * 64;
#pragma unroll
        for (int i = 0; i < 16; i++) {
            int idx = i * 256 + tid;
            int r = idx >> 6, c = idx & 63;
            tile[r][c] = f2bf(ws[(size_t)(e0 + r) * 1024 + u0 + c]);
        }
        __syncthreads();
#pragma unroll
        for (int i = 0; i < 16; i++) {
            int idx = i * 256 + tid;
            int r = idx >> 6, c = idx & 63;
            wst[(size_t)(u0 + r) * 1024 + e0 + c] = tile[c][r];
        }
    } else {
        const int b3 = bid - 16640;
        const int b = b3 & 31, ec = b3 >> 5;
        const int e0 = ec * 128;
        if (tid < 128) dS[tid] = dh[b * 1024 + e0 + tid];
        __syncthreads();
        f32x4 acc = {0.f, 0.f, 0.f, 0.f};
#pragma unroll 4
        for (int e = 0; e < 128; e++)
            acc += dS[e] * *(const f32x4*)(whk + (size_t)(e0 + e) * 1024 + tid * 4);
        *(f32x4*)(base_part + (size_t)ec * 32768 + b * 1024 + tid * 4) = acc;
    }
}

// ---------------------------------------------------------------------------
// K2 (fast): fused GEMM + tanh + dot(V). grid (512 row-stripes, 8 u-tiles):
// linear id % 8 == stripe % 8 -> all 8 u-tiles of a stripe share one XCD L2.
// Writes 8 score planes (wn halves LDS-combined). No atomics.
// ---------------------------------------------------------------------------
#define BM 128
#define BN 128
#define BK 32

__global__ __launch_bounds__(256) void score_gemm_fast(
    const unsigned short* __restrict__ encB,
    const unsigned short* __restrict__ wst,
    const float* __restrict__ base_part,      // [8][32*1024]
    const float* __restrict__ cov,
    const float* __restrict__ wc,
    const float* __restrict__ vk,
    const float* __restrict__ wsb, const float* __restrict__ whb,
    const float* __restrict__ wcb,
    const int* __restrict__ ucov,
    float* __restrict__ score_part)           // [8][65536]
{
    __shared__ unsigned short As[BM * BK];
    __shared__ unsigned short Bs[BN * BK];
    __shared__ float covS[BM];
    __shared__ float sred[2][BM];

    const int tid  = threadIdx.x;
    const int row0 = blockIdx.x * BM;
    const int u0   = blockIdx.y * BN;
    const int b    = row0 >> 11;
    const int use_cov = *ucov;

    if (tid < BM) covS[tid] = use_cov ? cov[row0 + tid] : 0.f;

    const int lane = tid & 63;
    const int wid  = tid >> 6;
    const int wm   = wid >> 1, wn = wid & 1;
    const int l16  = lane & 15, quad = lane >> 4;

    const int f0 = tid, f1 = 256 + tid;
    const int rA0 = f0 >> 2, rA1 = f1 >> 2;
    const int cA0 = ((f0 & 3) - rA0 - (rA0 >> 2)) & 3;
    const int cA1 = ((f1 & 3) - rA1 - (rA1 >> 2)) & 3;
    const unsigned short* pA0 = encB + (size_t)(row0 + rA0) * 1024 + cA0 * 8;
    const unsigned short* pA1 = encB + (size_t)(row0 + rA1) * 1024 + cA1 * 8;
    const unsigned short* pB0 = wst + (size_t)(u0 + rA0) * 1024 + cA0 * 8;
    const unsigned short* pB1 = wst + (size_t)(u0 + rA1) * 1024 + cA1 * 8;
    unsigned short* dA0 = As + f0 * 8;
    unsigned short* dA1 = As + f1 * 8;
    unsigned short* dB0 = Bs + f0 * 8;
    unsigned short* dB1 = Bs + f1 * 8;

    int offA[4], offB[4];
#pragma unroll
    for (int t = 0; t < 4; t++) {
        int ra = wm * 64 + t * 16 + l16;
        offA[t] = (ra * 4 + ((quad + ra + (ra >> 2)) & 3)) * 8;
        int rb = wn * 64 + t * 16 + l16;
        offB[t] = (rb * 4 + ((quad + rb + (rb >> 2)) & 3)) * 8;
    }

    f32x4 acc[4][4] = {};

    for (int kk = 0; kk < 1024 / BK; kk++) {
        __syncthreads();
        GLD16(pA0, dA0);
        GLD16(pA1, dA1);
        GLD16(pB0, dB0);
        GLD16(pB1, dB1);
        pA0 += BK; pA1 += BK; pB0 += BK; pB1 += BK;
        __syncthreads();

        short8 a[4], bb[4];
#pragma unroll
        for (int t = 0; t < 4; t++) {
            a[t]  = *(const short8*)&As[offA[t]];
            bb[t] = *(const short8*)&Bs[offB[t]];
        }
#pragma unroll
        for (int i = 0; i < 4; i++)
#pragma unroll
            for (int j = 0; j < 4; j++)
                acc[i][j] = __builtin_amdgcn_mfma_f32_16x16x32_bf16(a[i], bb[j], acc[i][j], 0, 0, 0);
    }

    float basev[4], wcv[4], vv[4];
#pragma unroll
    for (int j = 0; j < 4; j++) {
        int u = u0 + wn * 64 + j * 16 + l16;
        float bsum = wsb[u] + whb[u] + (use_cov ? wcb[u] : 0.f);
#pragma unroll
        for (int p = 0; p < 8; p++) bsum += base_part[p * 32768 + b * 1024 + u];
        basev[j] = bsum;
        wcv[j]   = use_cov ? wc[u] : 0.f;
        vv[j]    = vk[u];
    }
#pragma unroll
    for (int i = 0; i < 4; i++) {
        float part[4] = {0.f, 0.f, 0.f, 0.f};
#pragma unroll
        for (int r = 0; r < 4; r++) {
            float cv = covS[wm * 64 + i * 16 + quad * 4 + r];
#pragma unroll
            for (int j = 0; j < 4; j++)
                part[r] += fast_tanh(acc[i][j][r] + basev[j] + cv * wcv[j]) * vv[j];
        }
#pragma unroll
        for (int r = 0; r < 4; r++) {
            float v = part[r];
            v += __shfl_xor(v, 1);
            v += __shfl_xor(v, 2);
            v += __shfl_xor(v, 4);
            v += __shfl_xor(v, 8);
            if (l16 == 0) sred[wn][wm * 64 + i * 16 + quad * 4 + r] = v;
        }
    }
    __syncthreads();
    if (tid < BM)
        score_part[(size_t)blockIdx.y * 65536 + row0 + tid] = sred[0][tid] + sred[1][tid];
}

// ---------------------------------------------------------------------------
// K2 fallback (fp32 staging, atomics into plane 0)
// ---------------------------------------------------------------------------
#define LDT 40
__global__ __launch_bounds__(256) void score_gemm_f32(
    const float* __restrict__ enc, const unsigned short* __restrict__ wst,
    const float* __restrict__ base_part, const float* __restrict__ cov,
    const float* __restrict__ wc, const float* __restrict__ vk,
    const float* __restrict__ wsb, const float* __restrict__ whb,
    const float* __restrict__ wcb,
    const int* __restrict__ ucov, float* __restrict__ score)
{
    __shared__ unsigned short As[BM * LDT];
    __shared__ unsigned short Bs[BN * LDT];
    __shared__ float covS[BM];
    const int tid = threadIdx.x;
    const int row0 = blockIdx.x * BM, u0 = blockIdx.y * BN;
    const int b = row0 >> 11;
    const int use_cov = *ucov;
    if (tid < BM) covS[tid] = use_cov ? cov[row0 + tid] : 0.f;
    const int lane = tid & 63, wid = tid >> 6;
    const int wm = wid >> 1, wn = wid & 1;
    const int l16 = lane & 15, quad = lane >> 4;
    f32x4 acc[4][4] = {};
    for (int k0 = 0; k0 < 1024; k0 += BK) {
        __syncthreads();
#pragma unroll
        for (int i = 0; i < 4; i++) {
            int f = i * 256 + tid;
            int r = f >> 3, c4 = f & 7;
            const float* p = enc + (size_t)(row0 + r) * 1024 + k0 + c4 * 4;
            ushort4 w;
            w.x = f2bf(p[0]); w.y = f2bf(p[1]); w.z = f2bf(p[2]); w.w = f2bf(p[3]);
            *(ushort4*)&As[r * LDT + c4 * 4] = w;
        }
#pragma unroll
        for (int i = 0; i < 2; i++) {
            int f = i * 256 + tid;
            int r = f >> 2, c8 = f & 3;
            uint4 w = *(const uint4*)(wst + (size_t)(u0 + r) * 1024 + k0 + c8 * 8);
            *(uint4*)&Bs[r * LDT + c8 * 8] = w;
        }
        __syncthreads();
        short8 a[4], bb[4];
#pragma unroll
        for (int t = 0; t < 4; t++) {
            a[t]  = *(const short8*)&As[(wm * 64 + t * 16 + l16) * LDT + quad * 8];
            bb[t] = *(const short8*)&Bs[(wn * 64 + t * 16 + l16) * LDT + quad * 8];
        }
#pragma unroll
        for (int i = 0; i < 4; i++)
#pragma unroll
            for (int j = 0; j < 4; j++)
                acc[i][j] = __builtin_amdgcn_mfma_f32_16x16x32_bf16(a[i], bb[j], acc[i][j], 0, 0, 0);
    }
    float basev[4], wcv[4], vv[4];
#pragma unroll
    for (int j = 0; j < 4; j++) {
        int u = u0 + wn * 64 + j * 16 + l16;
        float bsum = wsb[u] + whb[u] + (use_cov ? wcb[u] : 0.f);
#pragma unroll
        for (int p = 0; p < 8; p++) bsum += base_part[p * 32768 + b * 1024 + u];
        basev[j] = bsum;
        wcv[j] = use_cov ? wc[u] : 0.f;
        vv[j] = vk[u];
    }
#pragma unroll
    for (int i = 0; i < 4; i++) {
        float part[4] = {0.f, 0.f, 0.f, 0.f};
#pragma unroll
        for (int r = 0; r < 4; r++) {
            float cv = covS[wm * 64 + i * 16 + quad * 4 + r];
#pragma unroll
            for (int j = 0; j < 4; j++)
                part[r] += fast_tanh(acc[i][j][r] + basev[j] + cv * wcv[j]) * vv[j];
        }
#pragma unroll
        for (int r = 0; r < 4; r++) {
            float v = part[r];
            v += __shfl_xor(v, 1);
            v += __shfl_xor(v, 2);
            v += __shfl_xor(v, 4);
            v += __shfl_xor(v, 8);
            if (l16 == 0)
                atomicAdd(&score[row0 + wm * 64 + i * 16 + quad * 4 + r], v);
        }
    }
}

// ---------------------------------------------------------------------------
// K3: softmax; sums nplanes score planes. grid 32 x 1024
// ---------------------------------------------------------------------------
__global__ __launch_bounds__(1024) void softmax_kernel(
    const float* __restrict__ score_part, int nplanes,
    const float* __restrict__ vb,
    const int* __restrict__ mask, const float* __restrict__ cov,
    const int* __restrict__ ucov,
    float* __restrict__ attn_out, float* __restrict__ cov_out)
{
    __shared__ float redA[16], redB[16];
    __shared__ float bc0, bc1;
    const int b = blockIdx.x, tid = threadIdx.x;
    const int i0 = b * 2048 + tid, i1 = i0 + 1024;
    const float vbv = vb[0];
    const int uc = *ucov;

    float s0 = 0.f, s1 = 0.f;
    for (int p = 0; p < nplanes; p++) {
        s0 += score_part[(size_t)p * 65536 + i0];
        s1 += score_part[(size_t)p * 65536 + i1];
    }
    s0 = (s0 + vbv) * (float)mask[i0];
    s1 = (s1 + vbv) * (float)mask[i1];

    float m = fmaxf(s0, s1);
#pragma unroll
    for (int off = 1; off < 64; off <<= 1) m = fmaxf(m, __shfl_xor(m, off));
    if ((tid & 63) == 0) redA[tid >> 6] = m;
    __syncthreads();
    if (tid < 16) {
        float v = redA[tid];
#pragma unroll
        for (int off = 1; off < 16; off <<= 1) v = fmaxf(v, __shfl_xor(v, off));
        if (tid == 0) bc0 = v;
    }
    __syncthreads();
    const float M = bc0;

    float e0 = __expf(s0 - M), e1 = __expf(s1 - M);
    float s = e0 + e1;
#pragma unroll
    for (int off = 1; off < 64; off <<= 1) s += __shfl_xor(s, off);
    if ((tid & 63) == 0) redB[tid >> 6] = s;
    __syncthreads();
    if (tid < 16) {
        float v = redB[tid];
#pragma unroll
        for (int off = 1; off < 16; off <<= 1) v += __shfl_xor(v, off);
        if (tid == 0) bc1 = v;
    }
    __syncthreads();
    const float inv = 1.f / bc1;

    float a0 = e0 * inv, a1 = e1 * inv;
    attn_out[i0] = a0;
    attn_out[i1] = a1;
    cov_out[i0] = a0 + (uc ? cov[i0] : 0.f);
    cov_out[i1] = a1 + (uc ? cov[i1] : 0.f);
}

// ---------------------------------------------------------------------------
// K4 (fast): context partials from bf16 enc. grid (32 b, 16 l-chunks) x 256.
// l-range split by tid>>7; halves combined via LDS; writes 16 planes.
// ---------------------------------------------------------------------------
__global__ __launch_bounds__(256) void context_bf16(const unsigned short* __restrict__ encB,
                                                    const float* __restrict__ attn,
                                                    float* __restrict__ ctx_part) {
    __shared__ float aS[128];
    __shared__ float cred[1024];
    const int b = blockIdx.x, lc = blockIdx.y, tid = threadIdx.x;
    const int l0 = lc * 128;
    if (tid < 128) aS[tid] = attn[b * 2048 + l0 + tid];
    __syncthreads();
    const int e8 = (tid & 127) * 8, r0 = tid >> 7;
    float acc[8] = {};
#pragma unroll 4
    for (int l = r0 * 64; l < r0 * 64 + 64; l++) {
        u16x8 w = *(const u16x8*)(encB + (size_t)(b * 2048 + l0 + l) * 1024 + e8);
        float a = aS[l];
#pragma unroll
        for (int j = 0; j < 8; j++) acc[j] = fmaf(a, bf2f(w[j]), acc[j]);
    }
    if (r0 == 1) {
#pragma unroll
        for (int j = 0; j < 8; j++) cred[e8 + j] = acc[j];
    }
    __syncthreads();
    if (r0 == 0) {
        float* o = ctx_part + (size_t)lc * 32768 + b * 1024 + e8;
#pragma unroll
        for (int j = 0; j < 8; j++) o[j] = acc[j] + cred[e8 + j];
    }
}

__global__ __launch_bounds__(1024) void ctx_reduce(const float* __restrict__ ctx_part,
                                                   float* __restrict__ out_ctx) {
    const int b = blockIdx.x, e = threadIdx.x;
    float s = 0.f;
#pragma unroll
    for (int p = 0; p < 16; p++) s += ctx_part[(size_t)p * 32768 + b * 1024 + e];
    out_ctx[b * 1024 + e] = s;
}

// K4 fallback: fp32 enc + atomics
__global__ __launch_bounds__(256) void context_f32(const float* __restrict__ enc,
                                                   const float* __restrict__ attn,
                                                   float* __restrict__ ctx) {
    __shared__ float aS[128];
    const int b = blockIdx.x, lc = blockIdx.y, tid = threadIdx.x;
    const int l0 = lc * 128;
    if (tid < 128) aS[tid] = attn[b * 2048 + l0 + tid];
    __syncthreads();
    const float* p = enc + ((size_t)(b * 2048 + l0)) * 1024 + tid * 4;
    f32x4 acc = {0.f, 0.f, 0.f, 0.f};
#pragma unroll 4
    for (int l = 0; l < 128; l++) acc += *(const f32x4*)(p + (size_t)l * 1024) * aS[l];
    float* o = ctx + b * 1024 + tid * 4;
    atomicAdd(o + 0, acc.x);
    atomicAdd(o + 1, acc.y);
    atomicAdd(o + 2, acc.z);
    atomicAdd(o + 3, acc.w);
}

// fallback prep: wst (256 blocks) + base partials (256 blocks)
__global__ __launch_bounds__(256) void prep2_kernel(
    const float* __restrict__ ws, unsigned short* __restrict__ wst,
    const float* __restrict__ dh, const float* __restrict__ whk,
    float* __restrict__ base_part)
{
    __shared__ unsigned short tile[64][65];
    __shared__ float dS[128];
    const int bid = blockIdx.x, tid = threadIdx.x;
    if (bid < 256) {
        const int e0 = (bid & 15) * 64, u0 = (bid >> 4) * 64;
#pragma unroll
        for (int i = 0; i < 16; i++) {
            int idx = i * 256 + tid;
            int r = idx >> 6, c = idx & 63;
            tile[r][c] = f2bf(ws[(size_t)(e0 + r) * 1024 + u0 + c]);
        }
        __syncthreads();
#pragma unroll
        for (int i = 0; i < 16; i++) {
            int idx = i * 256 + tid;
            int r = idx >> 6, c = idx & 63;
            wst[(size_t)(u0 + r) * 1024 + e0 + c] = tile[c][r];
        }
    } else {
        const int b3 = bid - 256;
        const int b = b3 & 31, ec = b3 >> 5;
        const int e0 = ec * 128;
        if (tid < 128) dS[tid] = dh[b * 1024 + e0 + tid];
        __syncthreads();
        f32x4 acc = {0.f, 0.f, 0.f, 0.f};
#pragma unroll 4
        for (int e = 0; e < 128; e++)
            acc += dS[e] * *(const f32x4*)(whk + (size_t)(e0 + e) * 1024 + tid * 4);
        *(f32x4*)(base_part + (size_t)ec * 32768 + b * 1024 + tid * 4) = acc;
    }
}

// ---------------------------------------------------------------------------
extern "C" void kernel_launch(void* const* d_in, const int* in_sizes, int n_in,
                              void* d_out, int out_size, void* d_ws, size_t ws_size,
                              hipStream_t stream) {
    const float* dec_hidden = (const float*)d_in[0];
    const float* enc        = (const float*)d_in[1];
    const float* prev_cov   = (const float*)d_in[2];
    const float* Ws_k       = (const float*)d_in[3];
    const float* Ws_b       = (const float*)d_in[4];
    const float* Wh_k       = (const float*)d_in[5];
    const float* Wh_b       = (const float*)d_in[6];
    const float* Wc_k       = (const float*)d_in[7];
    const float* Wc_b       = (const float*)d_in[8];
    const float* V_k        = (const float*)d_in[9];
    const float* V_b        = (const float*)d_in[10];
    const int*   mask       = (const int*)d_in[11];
    const int*   ucov       = (const int*)d_in[12];

    float* out_ctx  = (float*)d_out;
    float* out_attn = out_ctx + 32 * 1024;
    float* out_cov  = out_attn + 65536;

    char* ws = (char*)d_ws;
    unsigned short* wst = (unsigned short*)ws;                    // 2 MB
    float* base_part  = (float*)(ws + 2097152);                   // 1 MB  [8][32768]
    float* score_part = (float*)(ws + 3145728);                   // 2 MB  [8][65536]
    float* ctx_part   = score_part;                               // alias (score dead after softmax)
    unsigned short* encB = (unsigned short*)(ws + 5242880);       // 128 MB
    const size_t need_fast = 5242880 + (size_t)32 * 2048 * 1024 * 2;

    if (ws_size >= need_fast) {
        prep_kernel<<<16896, 256, 0, stream>>>(enc, encB, Ws_k, wst, dec_hidden, Wh_k, base_part);
        score_gemm_fast<<<dim3(512, 8), 256, 0, stream>>>(
            encB, wst, base_part, prev_cov, Wc_k, V_k, Ws_b, Wh_b, Wc_b, ucov, score_part);
        softmax_kernel<<<32, 1024, 0, stream>>>(score_part, 8, V_b, mask, prev_cov, ucov, out_attn, out_cov);
        context_bf16<<<dim3(32, 16), 256, 0, stream>>>(encB, out_attn, ctx_part);
        ctx_reduce<<<32, 1024, 0, stream>>>(ctx_part, out_ctx);
    } else {
        hipMemsetAsync(score_part, 0, 65536 * sizeof(float), stream);
        hipMemsetAsync(out_ctx, 0, 32 * 1024 * sizeof(float), stream);
        prep2_kernel<<<512, 256, 0, stream>>>(Ws_k, wst, dec_hidden, Wh_k, base_part);
        score_gemm_f32<<<dim3(512, 8), 256, 0, stream>>>(
            enc, wst, base_part, prev_cov, Wc_k, V_k, Ws_b, Wh_b, Wc_b, ucov, score_part);
        softmax_kernel<<<32, 1024, 0, stream>>>(score_part, 1, V_b, mask, prev_cov, ucov, out_attn, out_cov);
        context_f32<<<dim3(32, 16), 256, 0, stream>>>(enc, out_attn, out_ctx);
    }
}

// Round 4
// 651.479 us; speedup vs baseline: 1.1771x; 1.0266x over previous
//
#include <hip/hip_runtime.h>
#include <hip/hip_bf16.h>
#include <math.h>

typedef float f32x4 __attribute__((ext_vector_type(4)));
typedef short short8 __attribute__((ext_vector_type(8)));
typedef unsigned short u16x8 __attribute__((ext_vector_type(8)));

static __device__ __forceinline__ unsigned short f2bf(float f) {
    unsigned u = __builtin_bit_cast(unsigned, f);
    unsigned r = (u + 0x7FFFu + ((u >> 16) & 1u)) >> 16;
    return (unsigned short)r;
}
static __device__ __forceinline__ float bf2f(unsigned short h) {
    unsigned u = ((unsigned)h) << 16;
    return __builtin_bit_cast(float, u);
}
static __device__ __forceinline__ float fast_tanh(float x) {
    float ax = fminf(fmaxf(x, -9.f), 9.f);
    float e = __expf(2.f * ax);
    return 1.f - 2.f / (e + 1.f);
}

#define GLD16(g, l) __builtin_amdgcn_global_load_lds(                        \
    (const __attribute__((address_space(1))) void*)(g),                      \
    (__attribute__((address_space(3))) void*)(l), 16, 0, 0)

// ---------------------------------------------------------------------------
// PREP (fused): [0,16384): enc fp32->bf16; [16384,16640): Ws^T -> bf16;
// [16640,16896): base partials (8 e-chunks x 32 b)
// ---------------------------------------------------------------------------
__global__ __launch_bounds__(256) void prep_kernel(
    const float* __restrict__ enc, unsigned short* __restrict__ encB,
    const float* __restrict__ ws, unsigned short* __restrict__ wst,
    const float* __restrict__ dh, const float* __restrict__ whk,
    float* __restrict__ base_part)
{
    __shared__ unsigned short tile[64][65];
    __shared__ float dS[128];
    const int bid = blockIdx.x, tid = threadIdx.x;

    if (bid < 16384) {
        const size_t base0 = (size_t)bid * 4096;
#pragma unroll
        for (int i = 0; i < 4; i++) {
            size_t g = base0 + (size_t)i * 1024 + tid * 4;
            f32x4 v = *(const f32x4*)(enc + g);
            ushort4 w;
            w.x = f2bf(v.x); w.y = f2bf(v.y); w.z = f2bf(v.z); w.w = f2bf(v.w);
            *(ushort4*)(encB + g) = w;
        }
    } else if (bid < 16640) {
        const int b2 = bid - 16384;
        const int e0 = (b2 & 15) * 64, u0 = (b2 >> 4) * 64;
#pragma unroll
        for (int i = 0; i < 16; i++) {
            int idx = i * 256 + tid;
            int r = idx >> 6, c = idx & 63;
            tile[r][c] = f2bf(ws[(size_t)(e0 + r) * 1024 + u0 + c]);
        }
        __syncthreads();
#pragma unroll
        for (int i = 0; i < 16; i++) {
            int idx = i * 256 + tid;
            int r = idx >> 6, c = idx & 63;
            wst[(size_t)(u0 + r) * 1024 + e0 + c] = tile[c][r];
        }
    } else {
        const int b3 = bid - 16640;
        const int b = b3 & 31, ec = b3 >> 5;
        const int e0 = ec * 128;
        if (tid < 128) dS[tid] = dh[b * 1024 + e0 + tid];
        __syncthreads();
        f32x4 acc = {0.f, 0.f, 0.f, 0.f};
#pragma unroll 4
        for (int e = 0; e < 128; e++)
            acc += dS[e] * *(const f32x4*)(whk + (size_t)(e0 + e) * 1024 + tid * 4);
        *(f32x4*)(base_part + (size_t)ec * 32768 + b * 1024 + tid * 4) = acc;
    }
}

// ---------------------------------------------------------------------------
// K2 (fast): fused GEMM + tanh + dot(V). Double-buffered LDS, ONE barrier
// per K-iter: GLD(next) issued before compute(cur) so L2/L3 latency overlaps
// the MFMA block. Epilogue constants (base sum, wc, vk, cov) pre-staged in
// LDS to keep VGPRs low. grid (512 row-stripes, 8 u-tiles) x 256.
// ---------------------------------------------------------------------------
#define BM 128
#define BN 128
#define BK 32

__global__ __launch_bounds__(256) void score_gemm_fast(
    const unsigned short* __restrict__ encB,
    const unsigned short* __restrict__ wst,
    const float* __restrict__ base_part,      // [8][32*1024]
    const float* __restrict__ cov,
    const float* __restrict__ wc,
    const float* __restrict__ vk,
    const float* __restrict__ wsb, const float* __restrict__ whb,
    const float* __restrict__ wcb,
    const int* __restrict__ ucov,
    float* __restrict__ score_part)           // [8][65536]
{
    __shared__ unsigned short As[2][BM * BK]; // 2 x 8 KB
    __shared__ unsigned short Bs[2][BN * BK]; // 2 x 8 KB
    __shared__ float covS[BM];
    __shared__ float baseS[BN], wcS[BN], vvS[BN];
    __shared__ float sred[2][BM];

    const int tid  = threadIdx.x;
    const int row0 = blockIdx.x * BM;
    const int u0   = blockIdx.y * BN;
    const int b    = row0 >> 11;
    const int use_cov = *ucov;

    // stage epilogue constants (consumed only after final barrier)
    if (tid < BM) covS[tid] = use_cov ? cov[row0 + tid] : 0.f;
    if (tid < BN) {
        int u = u0 + tid;
        float s = wsb[u] + whb[u] + (use_cov ? wcb[u] : 0.f);
#pragma unroll
        for (int p = 0; p < 8; p++) s += base_part[p * 32768 + b * 1024 + u];
        baseS[tid] = s;
        wcS[tid]   = use_cov ? wc[u] : 0.f;
        vvS[tid]   = vk[u];
    }

    const int lane = tid & 63;
    const int wid  = tid >> 6;
    const int wm   = wid >> 1, wn = wid & 1;
    const int l16  = lane & 15, quad = lane >> 4;

    // staging chunk mapping (16B units); swizzled so ds_read_b128 is 2-way
    const int f0 = tid, f1 = 256 + tid;
    const int rA0 = f0 >> 2, rA1 = f1 >> 2;
    const int cA0 = ((f0 & 3) - rA0 - (rA0 >> 2)) & 3;
    const int cA1 = ((f1 & 3) - rA1 - (rA1 >> 2)) & 3;
    const unsigned short* pA0 = encB + (size_t)(row0 + rA0) * 1024 + cA0 * 8;
    const unsigned short* pA1 = encB + (size_t)(row0 + rA1) * 1024 + cA1 * 8;
    const unsigned short* pB0 = wst + (size_t)(u0 + rA0) * 1024 + cA0 * 8;
    const unsigned short* pB1 = wst + (size_t)(u0 + rA1) * 1024 + cA1 * 8;

    int offA[4], offB[4];
#pragma unroll
    for (int t = 0; t < 4; t++) {
        int ra = wm * 64 + t * 16 + l16;
        offA[t] = (ra * 4 + ((quad + ra + (ra >> 2)) & 3)) * 8;
        int rb = wn * 64 + t * 16 + l16;
        offB[t] = (rb * 4 + ((quad + rb + (rb >> 2)) & 3)) * 8;
    }

    f32x4 acc[4][4] = {};

    // preload k-tile 0 into buffer 0
    GLD16(pA0, &As[0][f0 * 8]);
    GLD16(pA1, &As[0][f1 * 8]);
    GLD16(pB0, &Bs[0][f0 * 8]);
    GLD16(pB1, &Bs[0][f1 * 8]);
    pA0 += BK; pA1 += BK; pB0 += BK; pB1 += BK;
    __syncthreads();

    for (int kk = 0; kk < 32; kk++) {
        const int cur = kk & 1, nxt = cur ^ 1;
        if (kk < 31) {
            GLD16(pA0, &As[nxt][f0 * 8]);
            GLD16(pA1, &As[nxt][f1 * 8]);
            GLD16(pB0, &Bs[nxt][f0 * 8]);
            GLD16(pB1, &Bs[nxt][f1 * 8]);
            pA0 += BK; pA1 += BK; pB0 += BK; pB1 += BK;
        }
        short8 a[4], bb[4];
#pragma unroll
        for (int t = 0; t < 4; t++) {
            a[t]  = *(const short8*)&As[cur][offA[t]];
            bb[t] = *(const short8*)&Bs[cur][offB[t]];
        }
#pragma unroll
        for (int i = 0; i < 4; i++)
#pragma unroll
            for (int j = 0; j < 4; j++)
                acc[i][j] = __builtin_amdgcn_mfma_f32_16x16x32_bf16(a[i], bb[j], acc[i][j], 0, 0, 0);
        __syncthreads();   // drains the GLDs issued above (overlapped w/ MFMA)
    }

    // epilogue: tanh(acc + base + cov*wc) * v, constants from LDS
#pragma unroll
    for (int i = 0; i < 4; i++) {
        float part[4] = {0.f, 0.f, 0.f, 0.f};
#pragma unroll
        for (int r = 0; r < 4; r++) {
            int rl = wm * 64 + i * 16 + quad * 4 + r;
            float cv = covS[rl];
#pragma unroll
            for (int j = 0; j < 4; j++) {
                int ul = wn * 64 + j * 16 + l16;
                float pre = acc[i][j][r] + baseS[ul] + cv * wcS[ul];
                part[r] += fast_tanh(pre) * vvS[ul];
            }
        }
#pragma unroll
        for (int r = 0; r < 4; r++) {
            float v = part[r];
            v += __shfl_xor(v, 1);
            v += __shfl_xor(v, 2);
            v += __shfl_xor(v, 4);
            v += __shfl_xor(v, 8);
            if (l16 == 0) sred[wn][wm * 64 + i * 16 + quad * 4 + r] = v;
        }
    }
    __syncthreads();
    if (tid < BM)
        score_part[(size_t)blockIdx.y * 65536 + row0 + tid] = sred[0][tid] + sred[1][tid];
}

// ---------------------------------------------------------------------------
// K3: softmax; sums nplanes score planes. grid 32 x 1024
// ---------------------------------------------------------------------------
__global__ __launch_bounds__(1024) void softmax_kernel(
    const float* __restrict__ score_part, int nplanes,
    const float* __restrict__ vb,
    const int* __restrict__ mask, const float* __restrict__ cov,
    const int* __restrict__ ucov,
    float* __restrict__ attn_out, float* __restrict__ cov_out)
{
    __shared__ float redA[16], redB[16];
    __shared__ float bc0, bc1;
    const int b = blockIdx.x, tid = threadIdx.x;
    const int i0 = b * 2048 + tid, i1 = i0 + 1024;
    const float vbv = vb[0];
    const int uc = *ucov;

    float s0 = 0.f, s1 = 0.f;
    for (int p = 0; p < nplanes; p++) {
        s0 += score_part[(size_t)p * 65536 + i0];
        s1 += score_part[(size_t)p * 65536 + i1];
    }
    s0 = (s0 + vbv) * (float)mask[i0];
    s1 = (s1 + vbv) * (float)mask[i1];

    float m = fmaxf(s0, s1);
#pragma unroll
    for (int off = 1; off < 64; off <<= 1) m = fmaxf(m, __shfl_xor(m, off));
    if ((tid & 63) == 0) redA[tid >> 6] = m;
    __syncthreads();
    if (tid < 16) {
        float v = redA[tid];
#pragma unroll
        for (int off = 1; off < 16; off <<= 1) v = fmaxf(v, __shfl_xor(v, off));
        if (tid == 0) bc0 = v;
    }
    __syncthreads();
    const float M = bc0;

    float e0 = __expf(s0 - M), e1 = __expf(s1 - M);
    float s = e0 + e1;
#pragma unroll
    for (int off = 1; off < 64; off <<= 1) s += __shfl_xor(s, off);
    if ((tid & 63) == 0) redB[tid >> 6] = s;
    __syncthreads();
    if (tid < 16) {
        float v = redB[tid];
#pragma unroll
        for (int off = 1; off < 16; off <<= 1) v += __shfl_xor(v, off);
        if (tid == 0) bc1 = v;
    }
    __syncthreads();
    const float inv = 1.f / bc1;

    float a0 = e0 * inv, a1 = e1 * inv;
    attn_out[i0] = a0;
    attn_out[i1] = a1;
    cov_out[i0] = a0 + (uc ? cov[i0] : 0.f);
    cov_out[i1] = a1 + (uc ? cov[i1] : 0.f);
}

// ---------------------------------------------------------------------------
// K4 (fast): context in ONE kernel. grid (32 b, 16 e-chunks of 64) x 256.
// Thread: 8 e-elems, l-stride 32. In-wave shuffle over l-partials, LDS
// cross-wave combine, direct stores to out_ctx. No atomics, no second pass.
// ---------------------------------------------------------------------------
__global__ __launch_bounds__(256) void context_bf16(const unsigned short* __restrict__ encB,
                                                    const float* __restrict__ attn,
                                                    float* __restrict__ out_ctx) {
    __shared__ float aS[2048];
    __shared__ float red[4][64];
    const int b = blockIdx.x, ec = blockIdx.y, tid = threadIdx.x;
    const int e0 = ec * 64;
    for (int i = tid; i < 2048; i += 256) aS[i] = attn[b * 2048 + i];
    __syncthreads();
    const int es = (tid & 7) * 8;
    const int lo = tid >> 3;
    float acc[8] = {};
    for (int l = lo; l < 2048; l += 32) {
        u16x8 w = *(const u16x8*)(encB + (size_t)(b * 2048 + l) * 1024 + e0 + es);
        float a = aS[l];
#pragma unroll
        for (int j = 0; j < 8; j++) acc[j] = fmaf(a, bf2f(w[j]), acc[j]);
    }
#pragma unroll
    for (int j = 0; j < 8; j++) {
        float v = acc[j];
        v += __shfl_xor(v, 8);
        v += __shfl_xor(v, 16);
        v += __shfl_xor(v, 32);
        acc[j] = v;
    }
    const int wv = tid >> 6;
    if ((tid & 63) < 8) {
#pragma unroll
        for (int j = 0; j < 8; j++) red[wv][(tid & 7) * 8 + j] = acc[j];
    }
    __syncthreads();
    if (tid < 64)
        out_ctx[b * 1024 + e0 + tid] = red[0][tid] + red[1][tid] + red[2][tid] + red[3][tid];
}

// ---------------------------------------------------------------------------
// Fallback path (ws too small for bf16 enc): fp32-staging gemm + atomics.
// ---------------------------------------------------------------------------
#define LDT 40
__global__ __launch_bounds__(256) void score_gemm_f32(
    const float* __restrict__ enc, const unsigned short* __restrict__ wst,
    const float* __restrict__ base_part, const float* __restrict__ cov,
    const float* __restrict__ wc, const float* __restrict__ vk,
    const float* __restrict__ wsb, const float* __restrict__ whb,
    const float* __restrict__ wcb,
    const int* __restrict__ ucov, float* __restrict__ score)
{
    __shared__ unsigned short As[BM * LDT];
    __shared__ unsigned short Bs[BN * LDT];
    __shared__ float covS[BM];
    __shared__ float baseS[BN], wcS[BN], vvS[BN];
    const int tid = threadIdx.x;
    const int row0 = blockIdx.x * BM, u0 = blockIdx.y * BN;
    const int b = row0 >> 11;
    const int use_cov = *ucov;
    if (tid < BM) covS[tid] = use_cov ? cov[row0 + tid] : 0.f;
    if (tid < BN) {
        int u = u0 + tid;
        float s = wsb[u] + whb[u] + (use_cov ? wcb[u] : 0.f);
#pragma unroll
        for (int p = 0; p < 8; p++) s += base_part[p * 32768 + b * 1024 + u];
        baseS[tid] = s;
        wcS[tid] = use_cov ? wc[u] : 0.f;
        vvS[tid] = vk[u];
    }
    const int lane = tid & 63, wid = tid >> 6;
    const int wm = wid >> 1, wn = wid & 1;
    const int l16 = lane & 15, quad = lane >> 4;
    f32x4 acc[4][4] = {};
    for (int k0 = 0; k0 < 1024; k0 += BK) {
        __syncthreads();
#pragma unroll
        for (int i = 0; i < 4; i++) {
            int f = i * 256 + tid;
            int r = f >> 3, c4 = f & 7;
            const float* p = enc + (size_t)(row0 + r) * 1024 + k0 + c4 * 4;
            ushort4 w;
            w.x = f2bf(p[0]); w.y = f2bf(p[1]); w.z = f2bf(p[2]); w.w = f2bf(p[3]);
            *(ushort4*)&As[r * LDT + c4 * 4] = w;
        }
#pragma unroll
        for (int i = 0; i < 2; i++) {
            int f = i * 256 + tid;
            int r = f >> 2, c8 = f & 3;
            uint4 w = *(const uint4*)(wst + (size_t)(u0 + r) * 1024 + k0 + c8 * 8);
            *(uint4*)&Bs[r * LDT + c8 * 8] = w;
        }
        __syncthreads();
        short8 a[4], bb[4];
#pragma unroll
        for (int t = 0; t < 4; t++) {
            a[t]  = *(const short8*)&As[(wm * 64 + t * 16 + l16) * LDT + quad * 8];
            bb[t] = *(const short8*)&Bs[(wn * 64 + t * 16 + l16) * LDT + quad * 8];
        }
#pragma unroll
        for (int i = 0; i < 4; i++)
#pragma unroll
            for (int j = 0; j < 4; j++)
                acc[i][j] = __builtin_amdgcn_mfma_f32_16x16x32_bf16(a[i], bb[j], acc[i][j], 0, 0, 0);
    }
#pragma unroll
    for (int i = 0; i < 4; i++) {
        float part[4] = {0.f, 0.f, 0.f, 0.f};
#pragma unroll
        for (int r = 0; r < 4; r++) {
            float cv = covS[wm * 64 + i * 16 + quad * 4 + r];
#pragma unroll
            for (int j = 0; j < 4; j++) {
                int ul = wn * 64 + j * 16 + l16;
                part[r] += fast_tanh(acc[i][j][r] + baseS[ul] + cv * wcS[ul]) * vvS[ul];
            }
        }
#pragma unroll
        for (int r = 0; r < 4; r++) {
            float v = part[r];
            v += __shfl_xor(v, 1);
            v += __shfl_xor(v, 2);
            v += __shfl_xor(v, 4);
            v += __shfl_xor(v, 8);
            if (l16 == 0)
                atomicAdd(&score[row0 + wm * 64 + i * 16 + quad * 4 + r], v);
        }
    }
}

__global__ __launch_bounds__(256) void context_f32(const float* __restrict__ enc,
                                                   const float* __restrict__ attn,
                                                   float* __restrict__ ctx) {
    __shared__ float aS[128];
    const int b = blockIdx.x, lc = blockIdx.y, tid = threadIdx.x;
    const int l0 = lc * 128;
    if (tid < 128) aS[tid] = attn[b * 2048 + l0 + tid];
    __syncthreads();
    const float* p = enc + ((size_t)(b * 2048 + l0)) * 1024 + tid * 4;
    f32x4 acc = {0.f, 0.f, 0.f, 0.f};
#pragma unroll 4
    for (int l = 0; l < 128; l++) acc += *(const f32x4*)(p + (size_t)l * 1024) * aS[l];
    float* o = ctx + b * 1024 + tid * 4;
    atomicAdd(o + 0, acc.x);
    atomicAdd(o + 1, acc.y);
    atomicAdd(o + 2, acc.z);
    atomicAdd(o + 3, acc.w);
}

__global__ __launch_bounds__(256) void prep2_kernel(
    const float* __restrict__ ws, unsigned short* __restrict__ wst,
    const float* __restrict__ dh, const float* __restrict__ whk,
    float* __restrict__ base_part)
{
    __shared__ unsigned short tile[64][65];
    __shared__ float dS[128];
    const int bid = blockIdx.x, tid = threadIdx.x;
    if (bid < 256) {
        const int e0 = (bid & 15) * 64, u0 = (bid >> 4) * 64;
#pragma unroll
        for (int i = 0; i < 16; i++) {
            int idx = i * 256 + tid;
            int r = idx >> 6, c = idx & 63;
            tile[r][c] = f2bf(ws[(size_t)(e0 + r) * 1024 + u0 + c]);
        }
        __syncthreads();
#pragma unroll
        for (int i = 0; i < 16; i++) {
            int idx = i * 256 + tid;
            int r = idx >> 6, c = idx & 63;
            wst[(size_t)(u0 + r) * 1024 + e0 + c] = tile[c][r];
        }
    } else {
        const int b3 = bid - 256;
        const int b = b3 & 31, ec = b3 >> 5;
        const int e0 = ec * 128;
        if (tid < 128) dS[tid] = dh[b * 1024 + e0 + tid];
        __syncthreads();
        f32x4 acc = {0.f, 0.f, 0.f, 0.f};
#pragma unroll 4
        for (int e = 0; e < 128; e++)
            acc += dS[e] * *(const f32x4*)(whk + (size_t)(e0 + e) * 1024 + tid * 4);
        *(f32x4*)(base_part + (size_t)ec * 32768 + b * 1024 + tid * 4) = acc;
    }
}

// ---------------------------------------------------------------------------
extern "C" void kernel_launch(void* const* d_in, const int* in_sizes, int n_in,
                              void* d_out, int out_size, void* d_ws, size_t ws_size,
                              hipStream_t stream) {
    const float* dec_hidden = (const float*)d_in[0];
    const float* enc        = (const float*)d_in[1];
    const float* prev_cov   = (const float*)d_in[2];
    const float* Ws_k       = (const float*)d_in[3];
    const float* Ws_b       = (const float*)d_in[4];
    const float* Wh_k       = (const float*)d_in[5];
    const float* Wh_b       = (const float*)d_in[6];
    const float* Wc_k       = (const float*)d_in[7];
    const float* Wc_b       = (const float*)d_in[8];
    const float* V_k        = (const float*)d_in[9];
    const float* V_b        = (const float*)d_in[10];
    const int*   mask       = (const int*)d_in[11];
    const int*   ucov       = (const int*)d_in[12];

    float* out_ctx  = (float*)d_out;
    float* out_attn = out_ctx + 32 * 1024;
    float* out_cov  = out_attn + 65536;

    char* ws = (char*)d_ws;
    unsigned short* wst = (unsigned short*)ws;                    // 2 MB
    float* base_part  = (float*)(ws + 2097152);                   // 1 MB  [8][32768]
    float* score_part = (float*)(ws + 3145728);                   // 2 MB  [8][65536]
    unsigned short* encB = (unsigned short*)(ws + 5242880);       // 128 MB
    const size_t need_fast = 5242880 + (size_t)32 * 2048 * 1024 * 2;

    if (ws_size >= need_fast) {
        prep_kernel<<<16896, 256, 0, stream>>>(enc, encB, Ws_k, wst, dec_hidden, Wh_k, base_part);
        score_gemm_fast<<<dim3(512, 8), 256, 0, stream>>>(
            encB, wst, base_part, prev_cov, Wc_k, V_k, Ws_b, Wh_b, Wc_b, ucov, score_part);
        softmax_kernel<<<32, 1024, 0, stream>>>(score_part, 8, V_b, mask, prev_cov, ucov, out_attn, out_cov);
        context_bf16<<<dim3(32, 16), 256, 0, stream>>>(encB, out_attn, out_ctx);
    } else {
        hipMemsetAsync(score_part, 0, 65536 * sizeof(float), stream);
        hipMemsetAsync(out_ctx, 0, 32 * 1024 * sizeof(float), stream);
        prep2_kernel<<<512, 256, 0, stream>>>(Ws_k, wst, dec_hidden, Wh_k, base_part);
        score_gemm_f32<<<dim3(512, 8), 256, 0, stream>>>(
            enc, wst, base_part, prev_cov, Wc_k, V_k, Ws_b, Wh_b, Wc_b, ucov, score_part);
        softmax_kernel<<<32, 1024, 0, stream>>>(score_part, 1, V_b, mask, prev_cov, ucov, out_attn, out_cov);
        context_f32<<<dim3(32, 16), 256, 0, stream>>>(enc, out_attn, out_ctx);
    }
}